// Round 1
// baseline (461.914 us; speedup 1.0000x reference)
//
#include <hip/hip_runtime.h>

#define MAXV 10000.0f

typedef float fx4 __attribute__((ext_vector_type(4)));

__device__ __forceinline__ float min3f(float a, float b, float c) {
    return fminf(fminf(a, b), c);
}

// 3x3 erosion, fp32. Each thread: 4-wide x R-tall column strip.
// Loads R+2 input rows once; rolling 3-row window in registers.
// R=32: vertical halo read redundancy (R+2)/R = 1.0625 (was 1.125 at R=16).
// XCD-chunked block swizzle: all y-tiles of one image stay on one XCD so
// halo rows shared by adjacent y-tiles hit that XCD's private L2.
// Non-temporal stores: output is never re-read; evict-first keeps input
// halo rows resident in L2.
template <int R>
__global__ __launch_bounds__(256)
void erode3x3_rows(const float* __restrict__ x,
                   const float* __restrict__ kern,
                   float* __restrict__ out,
                   int H, int W, int segs, int ytiles, int nwg) {
    // bijective XCD swizzle (physical blockIdx round-robins the 8 XCDs;
    // remap so each XCD gets a contiguous chunk of logical block ids)
    int bid = blockIdx.x;
    int lb  = bid;
    if ((nwg & 7) == 0) {
        const int cpx = nwg >> 3;              // chunks per XCD
        lb = (bid & 7) * cpx + (bid >> 3);
    }
    long long gid = (long long)lb * blockDim.x + threadIdx.x;
    int seg   = (int)(gid % segs);
    int ytile = (int)((gid / segs) % ytiles);
    long long bc = gid / ((long long)segs * ytiles);

    // structuring element (wave-uniform broadcast loads)
    float nv[3][3];
    bool all_active = true;
#pragma unroll
    for (int i = 0; i < 3; ++i)
#pragma unroll
        for (int j = 0; j < 3; ++j) {
            float kv = kern[i * 3 + j];
            nv[i][j] = (kv == 0.0f) ? -MAXV : 0.0f;
            all_active = all_active && (kv != 0.0f);
        }

    const int y0 = ytile * R;
    const int x0 = seg * 4;
    const float* base  = x   + bc * (long long)H * W;
    float*       obase = out + bc * (long long)H * W;

    if (all_active) {
        // separable: h = horizontal min3, out = vertical min3 of h
        fx4 ha = MAXV, hb = MAXV, hc = MAXV;
#pragma unroll 4
        for (int r = 0; r < R + 2; ++r) {
            const int ry = y0 - 1 + r;
            fx4 h;
            if (ry >= 0 && ry < H) {
                const float* rp = base + (long long)ry * W + x0;
                const fx4 b = *(const fx4*)rp;
                const float v0 = (seg > 0)        ? rp[-1] : MAXV;
                const float v5 = (seg < segs - 1) ? rp[4]  : MAXV;
                h.x = min3f(v0,  b.x, b.y);
                h.y = min3f(b.x, b.y, b.z);
                h.z = min3f(b.y, b.z, b.w);
                h.w = min3f(b.z, b.w, v5);
            } else {
                h = MAXV;
            }
            ha = hb; hb = hc; hc = h;
            if (r >= 2) {
                fx4 o;
                o.x = min3f(ha.x, hb.x, hc.x);
                o.y = min3f(ha.y, hb.y, hc.y);
                o.z = min3f(ha.z, hb.z, hc.z);
                o.w = min3f(ha.w, hb.w, hc.w);
                __builtin_nontemporal_store(
                    o, (fx4*)(obase + (long long)(ry - 1) * W + x0));
            }
        }
    } else {
        // generic: keep raw 6-wide rows, exact 9-tap with biases
        float a0[6], a1[6], a2[6];
#pragma unroll
        for (int j = 0; j < 6; ++j) { a0[j] = a1[j] = a2[j] = MAXV; }
#pragma unroll 2
        for (int r = 0; r < R + 2; ++r) {
            const int ry = y0 - 1 + r;
            float cur[6];
            if (ry >= 0 && ry < H) {
                const float* rp = base + (long long)ry * W + x0;
                const fx4 b = *(const fx4*)rp;
                cur[0] = (seg > 0)        ? rp[-1] : MAXV;
                cur[1] = b.x; cur[2] = b.y; cur[3] = b.z; cur[4] = b.w;
                cur[5] = (seg < segs - 1) ? rp[4]  : MAXV;
            } else {
#pragma unroll
                for (int j = 0; j < 6; ++j) cur[j] = MAXV;
            }
#pragma unroll
            for (int j = 0; j < 6; ++j) { a0[j] = a1[j]; a1[j] = a2[j]; a2[j] = cur[j]; }
            if (r >= 2) {
                float o[4];
#pragma unroll
                for (int e = 0; e < 4; ++e) {
                    float m = 3.4e38f;
#pragma unroll
                    for (int j = 0; j < 3; ++j) {
                        m = fminf(m, a0[e + j] - nv[0][j]);
                        m = fminf(m, a1[e + j] - nv[1][j]);
                        m = fminf(m, a2[e + j] - nv[2][j]);
                    }
                    o[e] = m;
                }
                fx4 ov; ov.x = o[0]; ov.y = o[1]; ov.z = o[2]; ov.w = o[3];
                __builtin_nontemporal_store(
                    ov, (fx4*)(obase + (long long)(ry - 1) * W + x0));
            }
        }
    }
}

extern "C" void kernel_launch(void* const* d_in, const int* in_sizes, int n_in,
                              void* d_out, int out_size, void* d_ws, size_t ws_size,
                              hipStream_t stream) {
    const float* x    = (const float*)d_in[0];
    const float* kern = (const float*)d_in[1];
    float* out        = (float*)d_out;

    const int H = 1024, W = 1024;
    constexpr int R = 32;                 // output rows per thread
    const int segs   = W / 4;             // 256 float4-segments per row
    const int ytiles = H / R;             // 32
    const long long BC = (long long)out_size / ((long long)H * W);  // 64

    const long long total = BC * (long long)ytiles * segs;  // threads
    const int block = 256;
    const long long grid = (total + block - 1) / block;     // 2048 (div by 8)

    erode3x3_rows<R><<<(dim3)(unsigned)grid, block, 0, stream>>>(
        x, kern, out, H, W, segs, ytiles, (int)grid);
}

// Round 2
// 454.560 us; speedup vs baseline: 1.0162x; 1.0162x over previous
//
#include <hip/hip_runtime.h>

#define MAXV 10000.0f

typedef float fx4 __attribute__((ext_vector_type(4)));

__device__ __forceinline__ float min3f(float a, float b, float c) {
    return fminf(fminf(a, b), c);
}

// 3x3 erosion, fp32. Each thread: 4-wide x R-tall column strip.
// Loads R+2 input rows once; rolling 3-row window in registers.
// R=16: 4096 blocks (16 blocks/CU) — known-good geometry from the 437.6 µs run.
// Plain stores (NOT nontemporal): round-1 A/B showed nt stores force the
// 262 MB output stream to HBM inside the kernel's critical path
// (2.4 TB/s effective, +67 µs on the dispatch). L2/L3 write absorption is
// the fast path here.
// XCD-chunked block swizzle kept: all y-tiles of one image stay on one XCD
// so halo rows shared by adjacent y-tiles hit that XCD's private L2.
template <int R>
__global__ __launch_bounds__(256)
void erode3x3_rows(const float* __restrict__ x,
                   const float* __restrict__ kern,
                   float* __restrict__ out,
                   int H, int W, int segs, int ytiles, int nwg) {
    // bijective XCD swizzle (physical blockIdx round-robins the 8 XCDs;
    // remap so each XCD gets a contiguous chunk of logical block ids)
    int bid = blockIdx.x;
    int lb  = bid;
    if ((nwg & 7) == 0) {
        const int cpx = nwg >> 3;              // chunks per XCD
        lb = (bid & 7) * cpx + (bid >> 3);
    }
    long long gid = (long long)lb * blockDim.x + threadIdx.x;
    int seg   = (int)(gid % segs);
    int ytile = (int)((gid / segs) % ytiles);
    long long bc = gid / ((long long)segs * ytiles);

    // structuring element (wave-uniform broadcast loads)
    float nv[3][3];
    bool all_active = true;
#pragma unroll
    for (int i = 0; i < 3; ++i)
#pragma unroll
        for (int j = 0; j < 3; ++j) {
            float kv = kern[i * 3 + j];
            nv[i][j] = (kv == 0.0f) ? -MAXV : 0.0f;
            all_active = all_active && (kv != 0.0f);
        }

    const int y0 = ytile * R;
    const int x0 = seg * 4;
    const float* base  = x   + bc * (long long)H * W;
    float*       obase = out + bc * (long long)H * W;

    if (all_active) {
        // separable: h = horizontal min3, out = vertical min3 of h
        fx4 ha = MAXV, hb = MAXV, hc = MAXV;
#pragma unroll
        for (int r = 0; r < R + 2; ++r) {
            const int ry = y0 - 1 + r;
            fx4 h;
            if (ry >= 0 && ry < H) {
                const float* rp = base + (long long)ry * W + x0;
                const fx4 b = *(const fx4*)rp;
                const float v0 = (seg > 0)        ? rp[-1] : MAXV;
                const float v5 = (seg < segs - 1) ? rp[4]  : MAXV;
                h.x = min3f(v0,  b.x, b.y);
                h.y = min3f(b.x, b.y, b.z);
                h.z = min3f(b.y, b.z, b.w);
                h.w = min3f(b.z, b.w, v5);
            } else {
                h = MAXV;
            }
            ha = hb; hb = hc; hc = h;
            if (r >= 2) {
                fx4 o;
                o.x = min3f(ha.x, hb.x, hc.x);
                o.y = min3f(ha.y, hb.y, hc.y);
                o.z = min3f(ha.z, hb.z, hc.z);
                o.w = min3f(ha.w, hb.w, hc.w);
                *(fx4*)(obase + (long long)(ry - 1) * W + x0) = o;
            }
        }
    } else {
        // generic: keep raw 6-wide rows, exact 9-tap with biases
        float a0[6], a1[6], a2[6];
#pragma unroll
        for (int j = 0; j < 6; ++j) { a0[j] = a1[j] = a2[j] = MAXV; }
#pragma unroll
        for (int r = 0; r < R + 2; ++r) {
            const int ry = y0 - 1 + r;
            float cur[6];
            if (ry >= 0 && ry < H) {
                const float* rp = base + (long long)ry * W + x0;
                const fx4 b = *(const fx4*)rp;
                cur[0] = (seg > 0)        ? rp[-1] : MAXV;
                cur[1] = b.x; cur[2] = b.y; cur[3] = b.z; cur[4] = b.w;
                cur[5] = (seg < segs - 1) ? rp[4]  : MAXV;
            } else {
#pragma unroll
                for (int j = 0; j < 6; ++j) cur[j] = MAXV;
            }
#pragma unroll
            for (int j = 0; j < 6; ++j) { a0[j] = a1[j]; a1[j] = a2[j]; a2[j] = cur[j]; }
            if (r >= 2) {
                float o[4];
#pragma unroll
                for (int e = 0; e < 4; ++e) {
                    float m = 3.4e38f;
#pragma unroll
                    for (int j = 0; j < 3; ++j) {
                        m = fminf(m, a0[e + j] - nv[0][j]);
                        m = fminf(m, a1[e + j] - nv[1][j]);
                        m = fminf(m, a2[e + j] - nv[2][j]);
                    }
                    o[e] = m;
                }
                fx4 ov; ov.x = o[0]; ov.y = o[1]; ov.z = o[2]; ov.w = o[3];
                *(fx4*)(obase + (long long)(ry - 1) * W + x0) = ov;
            }
        }
    }
}

extern "C" void kernel_launch(void* const* d_in, const int* in_sizes, int n_in,
                              void* d_out, int out_size, void* d_ws, size_t ws_size,
                              hipStream_t stream) {
    const float* x    = (const float*)d_in[0];
    const float* kern = (const float*)d_in[1];
    float* out        = (float*)d_out;

    const int H = 1024, W = 1024;
    constexpr int R = 16;                 // output rows per thread
    const int segs   = W / 4;             // 256 float4-segments per row
    const int ytiles = H / R;             // 64
    const long long BC = (long long)out_size / ((long long)H * W);  // 64

    const long long total = BC * (long long)ytiles * segs;  // threads
    const int block = 256;
    const long long grid = (total + block - 1) / block;     // 4096 (div by 8)

    erode3x3_rows<R><<<(dim3)(unsigned)grid, block, 0, stream>>>(
        x, kern, out, H, W, segs, ytiles, (int)grid);
}

// Round 3
// 449.416 us; speedup vs baseline: 1.0278x; 1.0114x over previous
//
#include <hip/hip_runtime.h>

#define MAXV 10000.0f

typedef float fx4 __attribute__((ext_vector_type(4)));

__device__ __forceinline__ float min3f(float a, float b, float c) {
    return fminf(fminf(a, b), c);
}

// 3x3 erosion, fp32. Each thread: 8-wide x R-tall column strip (two float4
// loads per row -> 2 independent 16B loads in flight per lane = 2x MLP vs
// the 4-wide version whose VGPR_Count=20 showed near-zero load overlap).
// Loads R+2 input rows once; rolling 3-row window in registers.
// R=16, 2048 blocks = 8 blocks/CU x 4 waves = full 32 waves/CU.
// Plain stores (round-1 A/B: nontemporal stores cost +67us on the dispatch).
// NO XCD swizzle (round-2 A/B: swizzle cost +17us total).
template <int R>
__global__ __launch_bounds__(256)
void erode3x3_rows(const float* __restrict__ x,
                   const float* __restrict__ kern,
                   float* __restrict__ out,
                   int H, int W, int segs, int ytiles) {
    long long gid = (long long)blockIdx.x * blockDim.x + threadIdx.x;
    int seg   = (int)(gid % segs);
    int ytile = (int)((gid / segs) % ytiles);
    long long bc = gid / ((long long)segs * ytiles);

    // structuring element (wave-uniform broadcast loads)
    float nv[3][3];
    bool all_active = true;
#pragma unroll
    for (int i = 0; i < 3; ++i)
#pragma unroll
        for (int j = 0; j < 3; ++j) {
            float kv = kern[i * 3 + j];
            nv[i][j] = (kv == 0.0f) ? -MAXV : 0.0f;
            all_active = all_active && (kv != 0.0f);
        }

    const int y0 = ytile * R;
    const int x0 = seg * 8;
    const float* base  = x   + bc * (long long)H * W;
    float*       obase = out + bc * (long long)H * W;

    if (all_active) {
        // separable: h = horizontal min3 (8 wide), out = vertical min3 of h
        fx4 ha0 = MAXV, ha1 = MAXV, hb0 = MAXV, hb1 = MAXV,
            hc0 = MAXV, hc1 = MAXV;
#pragma unroll
        for (int r = 0; r < R + 2; ++r) {
            const int ry = y0 - 1 + r;
            fx4 h0, h1;
            if (ry >= 0 && ry < H) {
                const float* rp = base + (long long)ry * W + x0;
                const fx4 b0 = *(const fx4*)rp;        // two independent
                const fx4 b1 = *(const fx4*)(rp + 4);  // 16B loads
                const float v0 = (seg > 0)        ? rp[-1] : MAXV;
                const float v9 = (seg < segs - 1) ? rp[8]  : MAXV;
                h0.x = min3f(v0,   b0.x, b0.y);
                h0.y = min3f(b0.x, b0.y, b0.z);
                h0.z = min3f(b0.y, b0.z, b0.w);
                h0.w = min3f(b0.z, b0.w, b1.x);
                h1.x = min3f(b0.w, b1.x, b1.y);
                h1.y = min3f(b1.x, b1.y, b1.z);
                h1.z = min3f(b1.y, b1.z, b1.w);
                h1.w = min3f(b1.z, b1.w, v9);
            } else {
                h0 = MAXV; h1 = MAXV;
            }
            ha0 = hb0; ha1 = hb1;
            hb0 = hc0; hb1 = hc1;
            hc0 = h0;  hc1 = h1;
            if (r >= 2) {
                fx4 o0, o1;
                o0.x = min3f(ha0.x, hb0.x, hc0.x);
                o0.y = min3f(ha0.y, hb0.y, hc0.y);
                o0.z = min3f(ha0.z, hb0.z, hc0.z);
                o0.w = min3f(ha0.w, hb0.w, hc0.w);
                o1.x = min3f(ha1.x, hb1.x, hc1.x);
                o1.y = min3f(ha1.y, hb1.y, hc1.y);
                o1.z = min3f(ha1.z, hb1.z, hc1.z);
                o1.w = min3f(ha1.w, hb1.w, hc1.w);
                float* op = obase + (long long)(ry - 1) * W + x0;
                *(fx4*)op       = o0;
                *(fx4*)(op + 4) = o1;
            }
        }
    } else {
        // generic: keep raw 10-wide rows, exact 9-tap with biases
        float a0[10], a1[10], a2[10];
#pragma unroll
        for (int j = 0; j < 10; ++j) { a0[j] = a1[j] = a2[j] = MAXV; }
#pragma unroll
        for (int r = 0; r < R + 2; ++r) {
            const int ry = y0 - 1 + r;
            float cur[10];
            if (ry >= 0 && ry < H) {
                const float* rp = base + (long long)ry * W + x0;
                const fx4 b0 = *(const fx4*)rp;
                const fx4 b1 = *(const fx4*)(rp + 4);
                cur[0] = (seg > 0)        ? rp[-1] : MAXV;
                cur[1] = b0.x; cur[2] = b0.y; cur[3] = b0.z; cur[4] = b0.w;
                cur[5] = b1.x; cur[6] = b1.y; cur[7] = b1.z; cur[8] = b1.w;
                cur[9] = (seg < segs - 1) ? rp[8]  : MAXV;
            } else {
#pragma unroll
                for (int j = 0; j < 10; ++j) cur[j] = MAXV;
            }
#pragma unroll
            for (int j = 0; j < 10; ++j) { a0[j] = a1[j]; a1[j] = a2[j]; a2[j] = cur[j]; }
            if (r >= 2) {
                float o[8];
#pragma unroll
                for (int e = 0; e < 8; ++e) {
                    float m = 3.4e38f;
#pragma unroll
                    for (int j = 0; j < 3; ++j) {
                        m = fminf(m, a0[e + j] - nv[0][j]);
                        m = fminf(m, a1[e + j] - nv[1][j]);
                        m = fminf(m, a2[e + j] - nv[2][j]);
                    }
                    o[e] = m;
                }
                fx4 ov0, ov1;
                ov0.x = o[0]; ov0.y = o[1]; ov0.z = o[2]; ov0.w = o[3];
                ov1.x = o[4]; ov1.y = o[5]; ov1.z = o[6]; ov1.w = o[7];
                float* op = obase + (long long)(ry - 1) * W + x0;
                *(fx4*)op       = ov0;
                *(fx4*)(op + 4) = ov1;
            }
        }
    }
}

extern "C" void kernel_launch(void* const* d_in, const int* in_sizes, int n_in,
                              void* d_out, int out_size, void* d_ws, size_t ws_size,
                              hipStream_t stream) {
    const float* x    = (const float*)d_in[0];
    const float* kern = (const float*)d_in[1];
    float* out        = (float*)d_out;

    const int H = 1024, W = 1024;
    constexpr int R = 16;                 // output rows per thread
    const int segs   = W / 8;             // 128 eight-float segments per row
    const int ytiles = H / R;             // 64
    const long long BC = (long long)out_size / ((long long)H * W);  // 64

    const long long total = BC * (long long)ytiles * segs;  // threads
    const int block = 256;
    const long long grid = (total + block - 1) / block;     // 2048

    erode3x3_rows<R><<<(dim3)(unsigned)grid, block, 0, stream>>>(
        x, kern, out, H, W, segs, ytiles);
}

// Round 4
// 439.464 us; speedup vs baseline: 1.0511x; 1.0226x over previous
//
#include <hip/hip_runtime.h>

#define MAXV 10000.0f

typedef float fx4 __attribute__((ext_vector_type(4)));

__device__ __forceinline__ float min3f(float a, float b, float c) {
    return fminf(fminf(a, b), c);
}

// 3x3 erosion, fp32. Round-0 geometry (proven best): thread = 4-wide x R=16
// column strip, 4096 blocks, default block order, plain fx4 stores.
// New in this version (fast path only):
//  1. ONE coalesced dwordx4 load per row: horizontal halo comes from
//     __shfl_up/__shfl_down (wave lanes hold consecutive segments); only
//     lanes 0/63 load a memory edge (exec-masked dword, 8B vs the old
//     512B/wave/row of redundant full-wave edge loads).
//  2. Explicit depth-4 software pipeline (statically-indexed ring, fully
//     unrolled): VGPR_Count=20 showed the compiler kept ~1 KB/wave in
//     flight; depth 4 keeps ~4 KB/wave so the read stream doesn't stall
//     a full HBM round-trip per row.
template <int R>
__global__ __launch_bounds__(256)
void erode3x3_rows(const float* __restrict__ x,
                   const float* __restrict__ kern,
                   float* __restrict__ out,
                   int H, int W, int segs, int ytiles) {
    long long gid = (long long)blockIdx.x * blockDim.x + threadIdx.x;
    int seg   = (int)(gid % segs);
    int ytile = (int)((gid / segs) % ytiles);
    long long bc = gid / ((long long)segs * ytiles);

    // structuring element (wave-uniform broadcast loads)
    float nv[3][3];
    bool all_active = true;
#pragma unroll
    for (int i = 0; i < 3; ++i)
#pragma unroll
        for (int j = 0; j < 3; ++j) {
            float kv = kern[i * 3 + j];
            nv[i][j] = (kv == 0.0f) ? -MAXV : 0.0f;
            all_active = all_active && (kv != 0.0f);
        }

    const int y0 = ytile * R;
    const int x0 = seg * 4;
    const float* base  = x   + bc * (long long)H * W;
    float*       obase = out + bc * (long long)H * W;

    if (all_active) {
        const int lane = threadIdx.x & 63;
        const bool is_l = (lane == 0);
        const bool is_r = (lane == 63);
        // does this lane need a memory edge value? (wave-edge lane, and not
        // at the image border where the pad is +MAXV)
        const bool has_edge = (is_l && seg > 0) || (is_r && seg + 1 < segs);
        const int  eoff = is_l ? -1 : 4;   // edge offset relative to rp

        constexpr int D = 4;               // prefetch depth
        fx4  pb[D];
        float pe[D];

        // issue load for pipeline stage r into slot s (r, s compile-time
        // after unroll -> registers, not scratch)
#define ISSUE(r_, s_)                                                      \
        {                                                                  \
            const int ry_ = y0 - 1 + (r_);                                 \
            if (ry_ >= 0 && ry_ < H) {                                     \
                const float* rp_ = base + (long long)ry_ * W + x0;         \
                pb[s_] = *(const fx4*)rp_;                                 \
                pe[s_] = MAXV;                                             \
                if (has_edge) pe[s_] = rp_[eoff];                          \
            } else {                                                       \
                pb[s_] = MAXV;                                             \
                pe[s_] = MAXV;                                             \
            }                                                              \
        }

#pragma unroll
        for (int r = 0; r < D; ++r) ISSUE(r, r);

        fx4 ha = MAXV, hb = MAXV, hc = MAXV;
#pragma unroll
        for (int r = 0; r < R + 2; ++r) {
            const fx4  b = pb[r % D];
            const float e = pe[r % D];
            // refill the slot we just consumed
            if (r + D < R + 2) ISSUE(r + D, r % D);

            // horizontal halo from wave shuffles; wave-edge lanes use e
            float left  = __shfl_up(b.w, 1, 64);
            float right = __shfl_down(b.x, 1, 64);
            left  = is_l ? e : left;
            right = is_r ? e : right;

            fx4 h;
            h.x = min3f(left, b.x, b.y);
            h.y = min3f(b.x,  b.y, b.z);
            h.z = min3f(b.y,  b.z, b.w);
            h.w = min3f(b.z,  b.w, right);

            ha = hb; hb = hc; hc = h;
            if (r >= 2) {
                const int ry = y0 - 1 + r;
                fx4 o;
                o.x = min3f(ha.x, hb.x, hc.x);
                o.y = min3f(ha.y, hb.y, hc.y);
                o.z = min3f(ha.z, hb.z, hc.z);
                o.w = min3f(ha.w, hb.w, hc.w);
                *(fx4*)(obase + (long long)(ry - 1) * W + x0) = o;
            }
        }
#undef ISSUE
    } else {
        // generic: keep raw 6-wide rows, exact 9-tap with biases
        float a0[6], a1[6], a2[6];
#pragma unroll
        for (int j = 0; j < 6; ++j) { a0[j] = a1[j] = a2[j] = MAXV; }
#pragma unroll
        for (int r = 0; r < R + 2; ++r) {
            const int ry = y0 - 1 + r;
            float cur[6];
            if (ry >= 0 && ry < H) {
                const float* rp = base + (long long)ry * W + x0;
                const fx4 b = *(const fx4*)rp;
                cur[0] = (seg > 0)        ? rp[-1] : MAXV;
                cur[1] = b.x; cur[2] = b.y; cur[3] = b.z; cur[4] = b.w;
                cur[5] = (seg < segs - 1) ? rp[4]  : MAXV;
            } else {
#pragma unroll
                for (int j = 0; j < 6; ++j) cur[j] = MAXV;
            }
#pragma unroll
            for (int j = 0; j < 6; ++j) { a0[j] = a1[j]; a1[j] = a2[j]; a2[j] = cur[j]; }
            if (r >= 2) {
                float o[4];
#pragma unroll
                for (int e = 0; e < 4; ++e) {
                    float m = 3.4e38f;
#pragma unroll
                    for (int j = 0; j < 3; ++j) {
                        m = fminf(m, a0[e + j] - nv[0][j]);
                        m = fminf(m, a1[e + j] - nv[1][j]);
                        m = fminf(m, a2[e + j] - nv[2][j]);
                    }
                    o[e] = m;
                }
                fx4 ov; ov.x = o[0]; ov.y = o[1]; ov.z = o[2]; ov.w = o[3];
                *(fx4*)(obase + (long long)(ry - 1) * W + x0) = ov;
            }
        }
    }
}

extern "C" void kernel_launch(void* const* d_in, const int* in_sizes, int n_in,
                              void* d_out, int out_size, void* d_ws, size_t ws_size,
                              hipStream_t stream) {
    const float* x    = (const float*)d_in[0];
    const float* kern = (const float*)d_in[1];
    float* out        = (float*)d_out;

    const int H = 1024, W = 1024;
    constexpr int R = 16;                 // output rows per thread
    const int segs   = W / 4;             // 256 float4-segments per row
    const int ytiles = H / R;             // 64
    const long long BC = (long long)out_size / ((long long)H * W);  // 64

    const long long total = BC * (long long)ytiles * segs;  // threads
    const int block = 256;
    const long long grid = (total + block - 1) / block;     // 4096

    erode3x3_rows<R><<<(dim3)(unsigned)grid, block, 0, stream>>>(
        x, kern, out, H, W, segs, ytiles);
}